// Round 1
// baseline (542.564 us; speedup 1.0000x reference)
//
#include <hip/hip_runtime.h>
#include <hip/hip_bf16.h>
#include <math.h>

// Problem constants (from reference setup_inputs)
#define BSZ 8
#define LSEQ 4096
#define HDIM 512
#define PDIM 256
#define MROWS (BSZ * LSEQ)        // 32768
#define KDIM 512                  // = HDIM for GEMM1, = 2*PDIM for GEMM2
#define NDIM 512                  // = 2*PDIM for GEMM1, = HDIM for GEMM2
#define CHUNK 64
#define NCHUNK (LSEQ / CHUNK)     // 64

// ---------------------------------------------------------------------------
// Precompute W1[h][n]: n=p -> Re(B_bar[p][h]), n=256+p -> Im(B_bar[p][h])
// B_bar = ((Lambda_bar - 1)/Lam) * B_tilde, Lambda_bar = exp(Lam*step).
// Done in double so transcendentals match the numpy reference.
// Also stores a_re/a_im = Lambda_bar (fp32) for the scan.
// ---------------------------------------------------------------------------
__global__ void precompute_w1(const float* __restrict__ Lre,
                              const float* __restrict__ Lim,
                              const float* __restrict__ logstep,
                              const float* __restrict__ Bmat,  // (P,H,2)
                              float* __restrict__ W1,
                              float* __restrict__ a_re,
                              float* __restrict__ a_im) {
    int idx = blockIdx.x * blockDim.x + threadIdx.x;  // p*H + h
    if (idx >= PDIM * HDIM) return;
    int p = idx / HDIM, h = idx % HDIM;
    double step = exp((double)logstep[p]);
    double dlr = (double)Lre[p], dli = (double)Lim[p];
    double mag = exp(dlr * step);
    double ar = mag * cos(dli * step);
    double ai = mag * sin(dli * step);
    double den = dlr * dlr + dli * dli;
    double nr = ar - 1.0, ni = ai;
    double fr = (nr * dlr + ni * dli) / den;
    double fi = (ni * dlr - nr * dli) / den;
    double br = (double)Bmat[(size_t)(p * HDIM + h) * 2 + 0];
    double bi = (double)Bmat[(size_t)(p * HDIM + h) * 2 + 1];
    W1[(size_t)h * NDIM + p]        = (float)(fr * br - fi * bi);
    W1[(size_t)h * NDIM + PDIM + p] = (float)(fr * bi + fi * br);
    if (h == 0) { a_re[p] = (float)ar; a_im[p] = (float)ai; }
}

// W2[k][h]: k=p -> 2*C_re[h][p]; k=256+p -> -2*C_im[h][p]
__global__ void precompute_w2(const float* __restrict__ Cmat,  // (H,P,2)
                              float* __restrict__ W2) {
    int idx = blockIdx.x * blockDim.x + threadIdx.x;  // h*P + p
    if (idx >= HDIM * PDIM) return;
    int h = idx / PDIM, p = idx % PDIM;
    float cr = Cmat[(size_t)(h * PDIM + p) * 2 + 0];
    float ci = Cmat[(size_t)(h * PDIM + p) * 2 + 1];
    W2[(size_t)p * HDIM + h]          = 2.0f * cr;
    W2[(size_t)(PDIM + p) * HDIM + h] = -2.0f * ci;
}

// ---------------------------------------------------------------------------
// fp32 SGEMM: C = A(MxK) * B(KxN) [+ Dvec[col]*Xskip row-wise]
// 128x128 tile, BK=16, 256 threads, 8x8 per thread.
// ---------------------------------------------------------------------------
#define TM_TILE 128
#define TN_TILE 128
#define TK_TILE 16

__global__ __launch_bounds__(256) void sgemm_kernel(
    const float* __restrict__ A, const float* __restrict__ B,
    float* __restrict__ C,
    const float* __restrict__ Dvec,   // nullable
    const float* __restrict__ Xskip,  // nullable
    int M, int N, int K) {
    __shared__ float As[TK_TILE][TM_TILE];  // transposed A tile
    __shared__ float Bs[TK_TILE][TN_TILE];

    const int tid = threadIdx.x;
    const int row0 = blockIdx.y * TM_TILE;
    const int col0 = blockIdx.x * TN_TILE;

    const int tm = (tid / 16) * 8;   // 0..120
    const int tn = (tid % 16) * 8;   // 0..120

    // A-load mapping: 2 float4 per thread (rows a_row, a_row+64; k = a_k..a_k+3)
    const int a_row = tid / 4;
    const int a_k = (tid % 4) * 4;
    // B-load mapping: 2 float4 per thread
    const int b_k = tid / 32;
    const int b_n = (tid % 32) * 4;

    float acc[8][8];
#pragma unroll
    for (int i = 0; i < 8; ++i)
#pragma unroll
        for (int j = 0; j < 8; ++j) acc[i][j] = 0.0f;

    for (int k0 = 0; k0 < K; k0 += TK_TILE) {
        float4 av0 = *(const float4*)&A[(size_t)(row0 + a_row) * K + k0 + a_k];
        float4 av1 = *(const float4*)&A[(size_t)(row0 + a_row + 64) * K + k0 + a_k];
        float4 bv0 = *(const float4*)&B[(size_t)(k0 + b_k) * N + col0 + b_n];
        float4 bv1 = *(const float4*)&B[(size_t)(k0 + b_k + 8) * N + col0 + b_n];

        As[a_k + 0][a_row] = av0.x;
        As[a_k + 1][a_row] = av0.y;
        As[a_k + 2][a_row] = av0.z;
        As[a_k + 3][a_row] = av0.w;
        As[a_k + 0][a_row + 64] = av1.x;
        As[a_k + 1][a_row + 64] = av1.y;
        As[a_k + 2][a_row + 64] = av1.z;
        As[a_k + 3][a_row + 64] = av1.w;
        *(float4*)&Bs[b_k][b_n] = bv0;
        *(float4*)&Bs[b_k + 8][b_n] = bv1;
        __syncthreads();

#pragma unroll
        for (int kk = 0; kk < TK_TILE; ++kk) {
            float a[8], bb[8];
            *(float4*)&a[0] = *(const float4*)&As[kk][tm];
            *(float4*)&a[4] = *(const float4*)&As[kk][tm + 4];
            *(float4*)&bb[0] = *(const float4*)&Bs[kk][tn];
            *(float4*)&bb[4] = *(const float4*)&Bs[kk][tn + 4];
#pragma unroll
            for (int i = 0; i < 8; ++i)
#pragma unroll
                for (int j = 0; j < 8; ++j) acc[i][j] += a[i] * bb[j];
        }
        __syncthreads();
    }

    const bool has_skip = (Dvec != nullptr);
#pragma unroll
    for (int i = 0; i < 8; ++i) {
        size_t r = (size_t)(row0 + tm + i);
#pragma unroll
        for (int j = 0; j < 8; j += 4) {
            int ccol = col0 + tn + j;
            float4 v = make_float4(acc[i][j], acc[i][j + 1], acc[i][j + 2], acc[i][j + 3]);
            if (has_skip) {
                const float4 xv = *(const float4*)&Xskip[r * N + ccol];
                v.x += Dvec[ccol + 0] * xv.x;
                v.y += Dvec[ccol + 1] * xv.y;
                v.z += Dvec[ccol + 2] * xv.z;
                v.w += Dvec[ccol + 3] * xv.w;
            }
            *(float4*)&C[r * N + ccol] = v;
        }
    }
}

// ---------------------------------------------------------------------------
// Scan pass A: per (b, chunk) block, per-p thread: local scan from zero over
// CHUNK steps; write chunk-end state.
// Bu layout: [m][n], n=p -> re, n=256+p -> im.
// ---------------------------------------------------------------------------
__global__ __launch_bounds__(256) void scan_chunks(const float* __restrict__ Bu,
                                                   const float* __restrict__ a_re,
                                                   const float* __restrict__ a_im,
                                                   float2* __restrict__ S) {
    int b = blockIdx.x / NCHUNK;
    int c = blockIdx.x % NCHUNK;
    int p = threadIdx.x;
    float ar = a_re[p], ai = a_im[p];
    float sr = 0.0f, si = 0.0f;
    size_t m0 = ((size_t)b * LSEQ + (size_t)c * CHUNK) * NDIM;
    for (int j = 0; j < CHUNK; ++j) {
        float ur = Bu[m0 + (size_t)j * NDIM + p];
        float ui = Bu[m0 + (size_t)j * NDIM + PDIM + p];
        float nsr = ar * sr - ai * si + ur;
        float nsi = ar * si + ai * sr + ui;
        sr = nsr;
        si = nsi;
    }
    S[(size_t)(b * NCHUNK + c) * PDIM + p] = make_float2(sr, si);
}

// Scan pass B: per (b,p): prefix over chunk states with decay a^CHUNK.
__global__ __launch_bounds__(256) void scan_carry(const float2* __restrict__ S,
                                                  const float* __restrict__ a_re,
                                                  const float* __restrict__ a_im,
                                                  float2* __restrict__ carry) {
    int b = blockIdx.x;
    int p = threadIdx.x;
    double ar = (double)a_re[p], ai = (double)a_im[p];
#pragma unroll
    for (int i = 0; i < 6; ++i) {  // a^64 via 6 squarings
        double nr = ar * ar - ai * ai;
        double ni = 2.0 * ar * ai;
        ar = nr;
        ai = ni;
    }
    float alr = (float)ar, ali = (float)ai;
    float cr = 0.0f, ci = 0.0f;
    for (int c = 0; c < NCHUNK; ++c) {
        carry[(size_t)(b * NCHUNK + c) * PDIM + p] = make_float2(cr, ci);
        float2 s = S[(size_t)(b * NCHUNK + c) * PDIM + p];
        float ncr = alr * cr - ali * ci + s.x;
        float nci = alr * ci + ali * cr + s.y;
        cr = ncr;
        ci = nci;
    }
}

// Scan pass C: local scan seeded with carry, write xs in place over Bu.
__global__ __launch_bounds__(256) void scan_apply(float* __restrict__ Bu,
                                                  const float* __restrict__ a_re,
                                                  const float* __restrict__ a_im,
                                                  const float2* __restrict__ carry) {
    int b = blockIdx.x / NCHUNK;
    int c = blockIdx.x % NCHUNK;
    int p = threadIdx.x;
    float ar = a_re[p], ai = a_im[p];
    float2 c0 = carry[(size_t)(b * NCHUNK + c) * PDIM + p];
    float sr = c0.x, si = c0.y;
    size_t m0 = ((size_t)b * LSEQ + (size_t)c * CHUNK) * NDIM;
    for (int j = 0; j < CHUNK; ++j) {
        size_t ir = m0 + (size_t)j * NDIM + p;
        size_t ii = m0 + (size_t)j * NDIM + PDIM + p;
        float ur = Bu[ir];
        float ui = Bu[ii];
        float nsr = ar * sr - ai * si + ur;
        float nsi = ar * si + ai * sr + ui;
        sr = nsr;
        si = nsi;
        Bu[ir] = sr;
        Bu[ii] = si;
    }
}

// ---------------------------------------------------------------------------
extern "C" void kernel_launch(void* const* d_in, const int* in_sizes, int n_in,
                              void* d_out, int out_size, void* d_ws, size_t ws_size,
                              hipStream_t stream) {
    const float* x       = (const float*)d_in[0];
    const float* Lre     = (const float*)d_in[1];
    const float* Lim     = (const float*)d_in[2];
    const float* Bmat    = (const float*)d_in[3];
    const float* Cmat    = (const float*)d_in[4];
    const float* Dvec    = (const float*)d_in[5];
    const float* logstep = (const float*)d_in[6];
    float* out = (float*)d_out;

    char* ws = (char*)d_ws;
    float*  W1    = (float*)(ws + 0);                   // 1 MB
    float*  W2    = (float*)(ws + (1u << 20));          // 1 MB
    float*  a_re  = (float*)(ws + (2u << 20));          // 1 KB
    float*  a_im  = (float*)(ws + (2u << 20) + 4096);   // 1 KB
    float2* S     = (float2*)(ws + (3u << 20));         // 1 MB
    float2* carry = (float2*)(ws + (4u << 20));         // 1 MB
    float*  Bu    = (float*)(ws + (5u << 20));          // 64 MB

    // 1. Precompute weight matrices (+ Lambda_bar)
    precompute_w1<<<(PDIM * HDIM + 255) / 256, 256, 0, stream>>>(
        Lre, Lim, logstep, Bmat, W1, a_re, a_im);
    precompute_w2<<<(HDIM * PDIM + 255) / 256, 256, 0, stream>>>(Cmat, W2);

    // 2. GEMM1: Bu = x @ W1
    dim3 ggrid(NDIM / TN_TILE, MROWS / TM_TILE);  // (4, 256)
    sgemm_kernel<<<ggrid, 256, 0, stream>>>(x, W1, Bu, nullptr, nullptr,
                                            MROWS, NDIM, KDIM);

    // 3. Scan (3-pass chunked)
    scan_chunks<<<BSZ * NCHUNK, 256, 0, stream>>>(Bu, a_re, a_im, S);
    scan_carry<<<BSZ, 256, 0, stream>>>(S, a_re, a_im, carry);
    scan_apply<<<BSZ * NCHUNK, 256, 0, stream>>>(Bu, a_re, a_im, carry);

    // 4. GEMM2: out = xs @ W2 + D*x
    sgemm_kernel<<<ggrid, 256, 0, stream>>>(Bu, W2, out, Dvec, x,
                                            MROWS, HDIM, 2 * PDIM);
}

// Round 2
// 271.465 us; speedup vs baseline: 1.9987x; 1.9987x over previous
//
#include <hip/hip_runtime.h>
#include <hip/hip_bf16.h>
#include <math.h>

// Problem constants
#define BSZ 8
#define LSEQ 4096
#define HDIM 512
#define PDIM 256
#define MROWS (BSZ * LSEQ)        // 32768
#define NDIM 512                  // 2*PDIM
#define CHUNK 64
#define NCHUNK (LSEQ / CHUNK)     // 64

typedef __attribute__((ext_vector_type(8))) short bf16x8;
typedef __attribute__((ext_vector_type(4))) float f32x4;

// ---------------------------------------------------------------------------
// x (fp32) -> xb (bf16), 4 elems/thread
// ---------------------------------------------------------------------------
__global__ __launch_bounds__(256) void convert_x(const float* __restrict__ x,
                                                 __hip_bfloat16* __restrict__ xb,
                                                 int n4) {
    int i = blockIdx.x * blockDim.x + threadIdx.x;
    if (i >= n4) return;
    float4 v = ((const float4*)x)[i];
    union { ushort4 u; __hip_bfloat16 h[4]; } o;
    o.h[0] = __float2bfloat16(v.x);
    o.h[1] = __float2bfloat16(v.y);
    o.h[2] = __float2bfloat16(v.z);
    o.h[3] = __float2bfloat16(v.w);
    ((ushort4*)xb)[i] = o.u;
}

// ---------------------------------------------------------------------------
// Precompute W1T (N x K = 512 x 512, bf16): row n=p -> Re(B_bar[p][h]) over h,
// row n=256+p -> Im(B_bar[p][h]).  Double precision transcendentals to match
// the numpy reference.  Also emits Lambda_bar (fp32) for the scan.
// ---------------------------------------------------------------------------
__global__ void precompute_w1(const float* __restrict__ Lre,
                              const float* __restrict__ Lim,
                              const float* __restrict__ logstep,
                              const float* __restrict__ Bmat,  // (P,H,2)
                              __hip_bfloat16* __restrict__ W1T,
                              float* __restrict__ a_re,
                              float* __restrict__ a_im) {
    int idx = blockIdx.x * blockDim.x + threadIdx.x;  // p*H + h
    if (idx >= PDIM * HDIM) return;
    int p = idx / HDIM, h = idx % HDIM;
    double step = exp((double)logstep[p]);
    double dlr = (double)Lre[p], dli = (double)Lim[p];
    double mag = exp(dlr * step);
    double ar = mag * cos(dli * step);
    double ai = mag * sin(dli * step);
    double den = dlr * dlr + dli * dli;
    double nr = ar - 1.0, ni = ai;
    double fr = (nr * dlr + ni * dli) / den;
    double fi = (ni * dlr - nr * dli) / den;
    double br = (double)Bmat[(size_t)(p * HDIM + h) * 2 + 0];
    double bi = (double)Bmat[(size_t)(p * HDIM + h) * 2 + 1];
    W1T[(size_t)p * HDIM + h]          = __float2bfloat16((float)(fr * br - fi * bi));
    W1T[(size_t)(PDIM + p) * HDIM + h] = __float2bfloat16((float)(fr * bi + fi * br));
    if (h == 0) { a_re[p] = (float)ar; a_im[p] = (float)ai; }
}

// W2T (N x K = 512 x 512, bf16): W2T[h][p] = 2*C_re[h][p]; W2T[h][256+p] = -2*C_im[h][p]
__global__ void precompute_w2(const float* __restrict__ Cmat,  // (H,P,2)
                              __hip_bfloat16* __restrict__ W2T) {
    int idx = blockIdx.x * blockDim.x + threadIdx.x;  // h*P + p
    if (idx >= HDIM * PDIM) return;
    int h = idx / PDIM, p = idx % PDIM;
    float cr = Cmat[(size_t)(h * PDIM + p) * 2 + 0];
    float ci = Cmat[(size_t)(h * PDIM + p) * 2 + 1];
    W2T[(size_t)h * NDIM + p]        = __float2bfloat16(2.0f * cr);
    W2T[(size_t)h * NDIM + PDIM + p] = __float2bfloat16(-2.0f * ci);
}

// ---------------------------------------------------------------------------
// bf16 MFMA GEMM, m97 structure: C(MxN,f32) = A(MxK,bf16) @ BT(NxK,bf16)^T
// 128x128 tile, BK=32, 256 threads = 4 waves in 2x2, each wave 4x4 of
// 16x16x32 MFMA.  global_load_lds width=16 staging.
// Optional fused skip: C += Dvec[col] * Xskip[m][col].
// ---------------------------------------------------------------------------
__global__ __launch_bounds__(256) void gemm_bt_bf16(
    const __hip_bfloat16* __restrict__ A,   // M x K
    const __hip_bfloat16* __restrict__ BT,  // N x K
    float* __restrict__ C,                  // M x N
    const float* __restrict__ Dvec,         // nullable
    const float* __restrict__ Xskip,        // nullable
    int M, int N, int K) {
    __shared__ __hip_bfloat16 smA[128 * 32];
    __shared__ __hip_bfloat16 smB[128 * 32];

    const int tid = threadIdx.x;
    const int lane = tid & 63;
    const int wave = tid >> 6;            // 0..3
    const int row0 = blockIdx.y * 128;
    const int col0 = blockIdx.x * 128;
    const int wm = (wave >> 1) * 64;
    const int wn = (wave & 1) * 64;

    // staging mapping: lane l -> row l/4 within a 16-row chunk, k-elems (l%4)*8
    const int sr = lane >> 2;
    const int sk = (lane & 3) * 8;
    const int quad = lane >> 4;           // 0..3
    const int l15 = lane & 15;

    f32x4 acc[4][4] = {};

    for (int k0 = 0; k0 < K; k0 += 32) {
#pragma unroll
        for (int q = 0; q < 2; ++q) {
            const int chunk = wave * 32 + q * 16;     // wave-uniform
            const int r = chunk + sr;
            const __hip_bfloat16* gA = A + (size_t)(row0 + r) * K + k0 + sk;
            const __hip_bfloat16* gB = BT + (size_t)(col0 + r) * K + k0 + sk;
            __builtin_amdgcn_global_load_lds(
                (const __attribute__((address_space(1))) void*)gA,
                (__attribute__((address_space(3))) void*)&smA[chunk * 32], 16, 0, 0);
            __builtin_amdgcn_global_load_lds(
                (const __attribute__((address_space(1))) void*)gB,
                (__attribute__((address_space(3))) void*)&smB[chunk * 32], 16, 0, 0);
        }
        __syncthreads();

        bf16x8 af[4], bfr[4];
#pragma unroll
        for (int i = 0; i < 4; ++i) {
            af[i]  = *(const bf16x8*)&smA[(wm + i * 16 + l15) * 32 + quad * 8];
            bfr[i] = *(const bf16x8*)&smB[(wn + i * 16 + l15) * 32 + quad * 8];
        }
#pragma unroll
        for (int i = 0; i < 4; ++i)
#pragma unroll
            for (int j = 0; j < 4; ++j)
                acc[i][j] = __builtin_amdgcn_mfma_f32_16x16x32_bf16(
                    af[i], bfr[j], acc[i][j], 0, 0, 0);
        __syncthreads();
    }

    // Epilogue: D row = quad*4 + r, col = l15  (m89/m91-verified mapping)
    const bool has_skip = (Xskip != nullptr);
#pragma unroll
    for (int i = 0; i < 4; ++i) {
        const int mbase = row0 + wm + i * 16 + quad * 4;
#pragma unroll
        for (int j = 0; j < 4; ++j) {
            const int col = col0 + wn + j * 16 + l15;
            const float dv = has_skip ? Dvec[col] : 0.0f;
#pragma unroll
            for (int r = 0; r < 4; ++r) {
                const size_t m = (size_t)(mbase + r);
                float v = acc[i][j][r];
                if (has_skip) v += dv * Xskip[m * N + col];
                C[m * N + col] = v;
            }
        }
    }
}

// ---------------------------------------------------------------------------
// Scan pass A: per (b, chunk), per-p thread: local scan from zero, write
// chunk-end state.  Bu layout [m][n] fp32, n=p re / n=256+p im.
// ---------------------------------------------------------------------------
__global__ __launch_bounds__(256) void scan_chunks(const float* __restrict__ Bu,
                                                   const float* __restrict__ a_re,
                                                   const float* __restrict__ a_im,
                                                   float2* __restrict__ S) {
    int b = blockIdx.x / NCHUNK;
    int c = blockIdx.x % NCHUNK;
    int p = threadIdx.x;
    float ar = a_re[p], ai = a_im[p];
    float sr = 0.0f, si = 0.0f;
    size_t m0 = ((size_t)b * LSEQ + (size_t)c * CHUNK) * NDIM;
    for (int j = 0; j < CHUNK; ++j) {
        float ur = Bu[m0 + (size_t)j * NDIM + p];
        float ui = Bu[m0 + (size_t)j * NDIM + PDIM + p];
        float nsr = ar * sr - ai * si + ur;
        float nsi = ar * si + ai * sr + ui;
        sr = nsr; si = nsi;
    }
    S[(size_t)(b * NCHUNK + c) * PDIM + p] = make_float2(sr, si);
}

// Scan pass B: per (b,p): exclusive prefix over chunk states, decay a^CHUNK.
__global__ __launch_bounds__(256) void scan_carry(const float2* __restrict__ S,
                                                  const float* __restrict__ a_re,
                                                  const float* __restrict__ a_im,
                                                  float2* __restrict__ carry) {
    int b = blockIdx.x;
    int p = threadIdx.x;
    double ar = (double)a_re[p], ai = (double)a_im[p];
#pragma unroll
    for (int i = 0; i < 6; ++i) {  // a^64 via squaring
        double nr = ar * ar - ai * ai;
        double ni = 2.0 * ar * ai;
        ar = nr; ai = ni;
    }
    float alr = (float)ar, ali = (float)ai;
    float cr = 0.0f, ci = 0.0f;
    for (int c = 0; c < NCHUNK; ++c) {
        carry[(size_t)(b * NCHUNK + c) * PDIM + p] = make_float2(cr, ci);
        float2 s = S[(size_t)(b * NCHUNK + c) * PDIM + p];
        float ncr = alr * cr - ali * ci + s.x;
        float nci = alr * ci + ali * cr + s.y;
        cr = ncr; ci = nci;
    }
}

// Scan pass C: local scan seeded with carry; write xs as bf16 (GEMM2 input).
__global__ __launch_bounds__(256) void scan_apply(const float* __restrict__ Bu,
                                                  const float* __restrict__ a_re,
                                                  const float* __restrict__ a_im,
                                                  const float2* __restrict__ carry,
                                                  __hip_bfloat16* __restrict__ xsb) {
    int b = blockIdx.x / NCHUNK;
    int c = blockIdx.x % NCHUNK;
    int p = threadIdx.x;
    float ar = a_re[p], ai = a_im[p];
    float2 c0 = carry[(size_t)(b * NCHUNK + c) * PDIM + p];
    float sr = c0.x, si = c0.y;
    size_t m0 = ((size_t)b * LSEQ + (size_t)c * CHUNK) * NDIM;
    for (int j = 0; j < CHUNK; ++j) {
        size_t base = m0 + (size_t)j * NDIM;
        float ur = Bu[base + p];
        float ui = Bu[base + PDIM + p];
        float nsr = ar * sr - ai * si + ur;
        float nsi = ar * si + ai * sr + ui;
        sr = nsr; si = nsi;
        xsb[base + p]        = __float2bfloat16(sr);
        xsb[base + PDIM + p] = __float2bfloat16(si);
    }
}

// ---------------------------------------------------------------------------
extern "C" void kernel_launch(void* const* d_in, const int* in_sizes, int n_in,
                              void* d_out, int out_size, void* d_ws, size_t ws_size,
                              hipStream_t stream) {
    const float* x       = (const float*)d_in[0];
    const float* Lre     = (const float*)d_in[1];
    const float* Lim     = (const float*)d_in[2];
    const float* Bmat    = (const float*)d_in[3];
    const float* Cmat    = (const float*)d_in[4];
    const float* Dvec    = (const float*)d_in[5];
    const float* logstep = (const float*)d_in[6];
    float* out = (float*)d_out;

    char* ws = (char*)d_ws;
    const size_t MB = 1u << 20;
    __hip_bfloat16* xb  = (__hip_bfloat16*)(ws + 0);         // 32 MB
    __hip_bfloat16* xsb = (__hip_bfloat16*)(ws + 32 * MB);   // 32 MB
    float*  Bu    = (float*)(ws + 64 * MB);                  // 64 MB
    __hip_bfloat16* W1T = (__hip_bfloat16*)(ws + 128 * MB);  // 0.5 MB
    __hip_bfloat16* W2T = (__hip_bfloat16*)(ws + 128 * MB + 512 * 1024);
    float*  a_re  = (float*)(ws + 129 * MB);
    float*  a_im  = (float*)(ws + 129 * MB + 4096);
    float2* S     = (float2*)(ws + 130 * MB);                // 1 MB
    float2* carry = (float2*)(ws + 131 * MB);                // 1 MB

    // 1. Conversions / precompute
    convert_x<<<(MROWS * HDIM / 4 + 255) / 256, 256, 0, stream>>>(
        x, xb, MROWS * HDIM / 4);
    precompute_w1<<<(PDIM * HDIM + 255) / 256, 256, 0, stream>>>(
        Lre, Lim, logstep, Bmat, W1T, a_re, a_im);
    precompute_w2<<<(HDIM * PDIM + 255) / 256, 256, 0, stream>>>(Cmat, W2T);

    // 2. GEMM1: Bu = xb @ W1T^T
    dim3 ggrid(NDIM / 128, MROWS / 128);  // (4, 256)
    gemm_bt_bf16<<<ggrid, 256, 0, stream>>>(xb, W1T, Bu, nullptr, nullptr,
                                            MROWS, NDIM, HDIM);

    // 3. Scan (3-pass chunked), emits xs as bf16
    scan_chunks<<<BSZ * NCHUNK, 256, 0, stream>>>(Bu, a_re, a_im, S);
    scan_carry<<<BSZ, 256, 0, stream>>>(S, a_re, a_im, carry);
    scan_apply<<<BSZ * NCHUNK, 256, 0, stream>>>(Bu, a_re, a_im, carry, xsb);

    // 4. GEMM2: out = xsb @ W2T^T + D*x
    gemm_bt_bf16<<<ggrid, 256, 0, stream>>>(xsb, W2T, out, Dvec, x,
                                            MROWS, HDIM, NDIM);
}

// Round 3
// 226.090 us; speedup vs baseline: 2.3998x; 1.2007x over previous
//
#include <hip/hip_runtime.h>
#include <hip/hip_bf16.h>
#include <hip/hip_fp16.h>
#include <math.h>

// Problem constants
#define BSZ 8
#define LSEQ 4096
#define HDIM 512
#define PDIM 256
#define MROWS (BSZ * LSEQ)        // 32768
#define NDIM 512                  // 2*PDIM
#define CHUNK 64
#define NCHUNK (LSEQ / CHUNK)     // 64

typedef __attribute__((ext_vector_type(8))) short bf16x8;
typedef __attribute__((ext_vector_type(4))) float f32x4;

// ---------------------------------------------------------------------------
// x (fp32) -> xb (bf16)
// ---------------------------------------------------------------------------
__global__ __launch_bounds__(256) void convert_x(const float* __restrict__ x,
                                                 __hip_bfloat16* __restrict__ xb,
                                                 int n4) {
    int i = blockIdx.x * blockDim.x + threadIdx.x;
    if (i >= n4) return;
    float4 v = ((const float4*)x)[i];
    union { ushort4 u; __hip_bfloat16 h[4]; } o;
    o.h[0] = __float2bfloat16(v.x);
    o.h[1] = __float2bfloat16(v.y);
    o.h[2] = __float2bfloat16(v.z);
    o.h[3] = __float2bfloat16(v.w);
    ((ushort4*)xb)[i] = o.u;
}

// ---------------------------------------------------------------------------
// W1T (bf16, N x K = 512 x 512): row 2p -> Re(B_bar[p][:]), row 2p+1 -> Im.
// Interleaved re/im so the scan gets half2-coalesced access.
// Double-precision transcendentals to match numpy ref. Emits Lambda_bar f32.
// ---------------------------------------------------------------------------
__global__ void precompute_w1(const float* __restrict__ Lre,
                              const float* __restrict__ Lim,
                              const float* __restrict__ logstep,
                              const float* __restrict__ Bmat,  // (P,H,2)
                              __hip_bfloat16* __restrict__ W1T,
                              float* __restrict__ a_re,
                              float* __restrict__ a_im) {
    int idx = blockIdx.x * blockDim.x + threadIdx.x;  // p*H + h
    if (idx >= PDIM * HDIM) return;
    int p = idx / HDIM, h = idx % HDIM;
    double step = exp((double)logstep[p]);
    double dlr = (double)Lre[p], dli = (double)Lim[p];
    double mag = exp(dlr * step);
    double ar = mag * cos(dli * step);
    double ai = mag * sin(dli * step);
    double den = dlr * dlr + dli * dli;
    double nr = ar - 1.0, ni = ai;
    double fr = (nr * dlr + ni * dli) / den;
    double fi = (ni * dlr - nr * dli) / den;
    double br = (double)Bmat[(size_t)(p * HDIM + h) * 2 + 0];
    double bi = (double)Bmat[(size_t)(p * HDIM + h) * 2 + 1];
    W1T[(size_t)(2 * p) * HDIM + h]     = __float2bfloat16((float)(fr * br - fi * bi));
    W1T[(size_t)(2 * p + 1) * HDIM + h] = __float2bfloat16((float)(fr * bi + fi * br));
    if (h == 0) { a_re[p] = (float)ar; a_im[p] = (float)ai; }
}

// W2T (bf16, N x K = 512 x 512): W2T[h][2p] = 2*C_re[h][p]; [h][2p+1] = -2*C_im[h][p]
__global__ void precompute_w2(const float* __restrict__ Cmat,  // (H,P,2)
                              __hip_bfloat16* __restrict__ W2T) {
    int idx = blockIdx.x * blockDim.x + threadIdx.x;  // h*P + p
    if (idx >= HDIM * PDIM) return;
    int h = idx / PDIM, p = idx % PDIM;
    float cr = Cmat[(size_t)(h * PDIM + p) * 2 + 0];
    float ci = Cmat[(size_t)(h * PDIM + p) * 2 + 1];
    W2T[(size_t)h * NDIM + 2 * p]     = __float2bfloat16(2.0f * cr);
    W2T[(size_t)h * NDIM + 2 * p + 1] = __float2bfloat16(-2.0f * ci);
}

// ---------------------------------------------------------------------------
// bf16 MFMA GEMM: C(MxN, OT) = A(MxK,bf16) @ BT(NxK,bf16)^T [+ D*xskip]
// 64x128 tile, BK=32, 256 threads = 4 waves (2x2), each wave 2x4 frags of
// 16x16x32.  Grid 2048 blocks -> 8 blocks/CU for latency hiding.
// ---------------------------------------------------------------------------
template <typename OT, bool SKIP>
__global__ __launch_bounds__(256) void gemm_bt(
    const __hip_bfloat16* __restrict__ A,   // M x K
    const __hip_bfloat16* __restrict__ BT,  // N x K
    OT* __restrict__ C,                     // M x N
    const float* __restrict__ Dvec,
    const __hip_bfloat16* __restrict__ Xskip,
    int M, int N, int K) {
    __shared__ __hip_bfloat16 smA[64 * 32];    // 4 KB
    __shared__ __hip_bfloat16 smB[128 * 32];   // 8 KB

    const int tid = threadIdx.x;
    const int lane = tid & 63;
    const int wave = tid >> 6;            // 0..3
    const int row0 = blockIdx.y * 64;
    const int col0 = blockIdx.x * 128;
    const int wm = (wave >> 1) * 32;
    const int wn = (wave & 1) * 64;

    const int sr = lane >> 2;             // 0..15
    const int sk = (lane & 3) * 8;
    const int quad = lane >> 4;           // 0..3
    const int l15 = lane & 15;

    f32x4 acc[2][4] = {};

    for (int k0 = 0; k0 < K; k0 += 32) {
        {   // A staging: 64 rows, 1 issue/wave
            const int chunk = wave * 16;
            const __hip_bfloat16* gA = A + (size_t)(row0 + chunk + sr) * K + k0 + sk;
            __builtin_amdgcn_global_load_lds(
                (const __attribute__((address_space(1))) void*)gA,
                (__attribute__((address_space(3))) void*)&smA[chunk * 32], 16, 0, 0);
        }
#pragma unroll
        for (int q = 0; q < 2; ++q) {     // B staging: 128 rows, 2 issues/wave
            const int chunk = wave * 32 + q * 16;
            const __hip_bfloat16* gB = BT + (size_t)(col0 + chunk + sr) * K + k0 + sk;
            __builtin_amdgcn_global_load_lds(
                (const __attribute__((address_space(1))) void*)gB,
                (__attribute__((address_space(3))) void*)&smB[chunk * 32], 16, 0, 0);
        }
        __syncthreads();

        bf16x8 af[2], bfr[4];
#pragma unroll
        for (int i = 0; i < 2; ++i)
            af[i] = *(const bf16x8*)&smA[(wm + i * 16 + l15) * 32 + quad * 8];
#pragma unroll
        for (int j = 0; j < 4; ++j)
            bfr[j] = *(const bf16x8*)&smB[(wn + j * 16 + l15) * 32 + quad * 8];
#pragma unroll
        for (int i = 0; i < 2; ++i)
#pragma unroll
            for (int j = 0; j < 4; ++j)
                acc[i][j] = __builtin_amdgcn_mfma_f32_16x16x32_bf16(
                    af[i], bfr[j], acc[i][j], 0, 0, 0);
        __syncthreads();
    }

    // Epilogue: D row = quad*4 + r, col = l15 (m89/m91-verified)
#pragma unroll
    for (int i = 0; i < 2; ++i) {
        const int mbase = row0 + wm + i * 16 + quad * 4;
#pragma unroll
        for (int j = 0; j < 4; ++j) {
            const int col = col0 + wn + j * 16 + l15;
            const float dv = SKIP ? Dvec[col] : 0.0f;
#pragma unroll
            for (int r = 0; r < 4; ++r) {
                const size_t m = (size_t)(mbase + r);
                float v = acc[i][j][r];
                if (SKIP) v += dv * __bfloat162float(Xskip[m * N + col]);
                if constexpr (sizeof(OT) == 2) {
                    C[m * N + col] = OT(v);
                } else {
                    C[m * N + col] = v;
                }
            }
        }
    }
}

// ---------------------------------------------------------------------------
// Scan pass A: per (b, chunk), per-p thread: local scan from zero over CHUNK
// steps; write chunk-end state.  Bu fp16 interleaved: [m][2p]=re, [m][2p+1]=im.
// ---------------------------------------------------------------------------
__global__ __launch_bounds__(256) void scan_chunks(const __half2* __restrict__ Bu2,
                                                   const float* __restrict__ a_re,
                                                   const float* __restrict__ a_im,
                                                   float2* __restrict__ S) {
    int b = blockIdx.x / NCHUNK;
    int c = blockIdx.x % NCHUNK;
    int p = threadIdx.x;
    float ar = a_re[p], ai = a_im[p];
    float sr = 0.0f, si = 0.0f;
    size_t m0 = (size_t)b * LSEQ + (size_t)c * CHUNK;
    for (int j = 0; j < CHUNK; ++j) {
        float2 u = __half22float2(Bu2[(m0 + j) * PDIM + p]);
        float nsr = ar * sr - ai * si + u.x;
        float nsi = ar * si + ai * sr + u.y;
        sr = nsr; si = nsi;
    }
    S[(size_t)(b * NCHUNK + c) * PDIM + p] = make_float2(sr, si);
}

// Scan pass B: per (b,p): exclusive prefix over chunk states, decay a^CHUNK.
__global__ __launch_bounds__(256) void scan_carry(const float2* __restrict__ S,
                                                  const float* __restrict__ a_re,
                                                  const float* __restrict__ a_im,
                                                  float2* __restrict__ carry) {
    int b = blockIdx.x;
    int p = threadIdx.x;
    double ar = (double)a_re[p], ai = (double)a_im[p];
#pragma unroll
    for (int i = 0; i < 6; ++i) {
        double nr = ar * ar - ai * ai;
        double ni = 2.0 * ar * ai;
        ar = nr; ai = ni;
    }
    float alr = (float)ar, ali = (float)ai;
    float cr = 0.0f, ci = 0.0f;
    for (int c = 0; c < NCHUNK; ++c) {
        carry[(size_t)(b * NCHUNK + c) * PDIM + p] = make_float2(cr, ci);
        float2 s = S[(size_t)(b * NCHUNK + c) * PDIM + p];
        float ncr = alr * cr - ali * ci + s.x;
        float nci = alr * ci + ali * cr + s.y;
        cr = ncr; ci = nci;
    }
}

// Scan pass C: local scan seeded with carry; write xs as bf16 (interleaved).
__global__ __launch_bounds__(256) void scan_apply(const __half2* __restrict__ Bu2,
                                                  const float* __restrict__ a_re,
                                                  const float* __restrict__ a_im,
                                                  const float2* __restrict__ carry,
                                                  ushort2* __restrict__ xsb2) {
    int b = blockIdx.x / NCHUNK;
    int c = blockIdx.x % NCHUNK;
    int p = threadIdx.x;
    float ar = a_re[p], ai = a_im[p];
    float2 c0 = carry[(size_t)(b * NCHUNK + c) * PDIM + p];
    float sr = c0.x, si = c0.y;
    size_t m0 = (size_t)b * LSEQ + (size_t)c * CHUNK;
    for (int j = 0; j < CHUNK; ++j) {
        size_t idx = (m0 + j) * PDIM + p;
        float2 u = __half22float2(Bu2[idx]);
        float nsr = ar * sr - ai * si + u.x;
        float nsi = ar * si + ai * sr + u.y;
        sr = nsr; si = nsi;
        union { ushort2 u2; __hip_bfloat16 h[2]; } o;
        o.h[0] = __float2bfloat16(sr);
        o.h[1] = __float2bfloat16(si);
        xsb2[idx] = o.u2;
    }
}

// ---------------------------------------------------------------------------
extern "C" void kernel_launch(void* const* d_in, const int* in_sizes, int n_in,
                              void* d_out, int out_size, void* d_ws, size_t ws_size,
                              hipStream_t stream) {
    const float* x       = (const float*)d_in[0];
    const float* Lre     = (const float*)d_in[1];
    const float* Lim     = (const float*)d_in[2];
    const float* Bmat    = (const float*)d_in[3];
    const float* Cmat    = (const float*)d_in[4];
    const float* Dvec    = (const float*)d_in[5];
    const float* logstep = (const float*)d_in[6];
    float* out = (float*)d_out;

    char* ws = (char*)d_ws;
    const size_t MB = 1u << 20;
    __hip_bfloat16* xb  = (__hip_bfloat16*)(ws + 0);         // 32 MB
    __hip_bfloat16* xsb = (__hip_bfloat16*)(ws + 32 * MB);   // 32 MB
    __half* Bu          = (__half*)(ws + 64 * MB);           // 32 MB
    __hip_bfloat16* W1T = (__hip_bfloat16*)(ws + 96 * MB);   // 0.5 MB
    __hip_bfloat16* W2T = (__hip_bfloat16*)(ws + 96 * MB + 512 * 1024);
    float*  a_re  = (float*)(ws + 97 * MB);
    float*  a_im  = (float*)(ws + 97 * MB + 4096);
    float2* S     = (float2*)(ws + 98 * MB);                 // 1 MB
    float2* carry = (float2*)(ws + 99 * MB);                 // 1 MB

    // 1. Conversions / precompute
    convert_x<<<(MROWS * HDIM / 4 + 255) / 256, 256, 0, stream>>>(
        x, xb, MROWS * HDIM / 4);
    precompute_w1<<<(PDIM * HDIM + 255) / 256, 256, 0, stream>>>(
        Lre, Lim, logstep, Bmat, W1T, a_re, a_im);
    precompute_w2<<<(HDIM * PDIM + 255) / 256, 256, 0, stream>>>(Cmat, W2T);

    // 2. GEMM1: Bu(fp16) = xb @ W1T^T
    dim3 ggrid(NDIM / 128, MROWS / 64);  // (4, 512) = 2048 blocks
    gemm_bt<__half, false><<<ggrid, 256, 0, stream>>>(
        xb, W1T, Bu, nullptr, nullptr, MROWS, NDIM, HDIM);

    // 3. Scan (3-pass chunked), emits xs as bf16
    scan_chunks<<<BSZ * NCHUNK, 256, 0, stream>>>((const __half2*)Bu, a_re, a_im, S);
    scan_carry<<<BSZ, 256, 0, stream>>>(S, a_re, a_im, carry);
    scan_apply<<<BSZ * NCHUNK, 256, 0, stream>>>((const __half2*)Bu, a_re, a_im,
                                                 carry, (ushort2*)xsb);

    // 4. GEMM2: out = xsb @ W2T^T + D*xb
    gemm_bt<float, true><<<ggrid, 256, 0, stream>>>(
        xsb, W2T, out, Dvec, xb, MROWS, HDIM, NDIM);
}